// Round 10
// baseline (503.730 us; speedup 1.0000x reference)
//
#include <hip/hip_runtime.h>

typedef float f4   __attribute__((ext_vector_type(4)));
typedef float f2   __attribute__((ext_vector_type(2)));
typedef _Float16 f16x8 __attribute__((ext_vector_type(8)));
typedef float f32x4  __attribute__((ext_vector_type(4)));

#define N_ROWS  32768
#define D_DIM   256
#define K_CODES 8192
#define NUM_ELEM (N_ROWS * D_DIM)
#define EPS_MARGIN 2e-3f     // fp16 single-pass sieve: key-diff err sigma ~2.6e-4 -> 7.7 sigma
#define FB_CAP  8192
#define FB_RPB  16           // rows per refine chunk
#define RF_SLICES 32         // code slices of 256
#define N_PANELS 256         // 32 codes per panel
#define HALF_PANELS 128      // panels per code-half

__device__ __forceinline__ void gl2lds16(const void* g, void* l) {
    __builtin_amdgcn_global_load_lds(
        (const __attribute__((address_space(1))) unsigned int*)g,
        (__attribute__((address_space(3))) unsigned int*)l, 16, 0, 0);
}

// -------- fused prep: ctl-zero + Ep (panel-major fp16) + Et32 (E^T fp32) + ee --------
__global__ void prep_kernel(const float* __restrict__ E, short* __restrict__ Ep,
                            float* __restrict__ Et32, float* __restrict__ ee,
                            float* __restrict__ ctl) {
    __shared__ float eepart[8][32];
    const int p  = blockIdx.x;
    const int t  = threadIdx.x;
    const int c  = t & 31;
    const int gq = t >> 5;
    const int cp = p * 32;
    if (p == 0) {   // zero control region [0, 8192): loss_sum, counter, patch_done, ready[256]
        f4 z = (f4)(0.0f);
        f4* dst = (f4*)ctl;
        dst[t * 2]     = z;
        dst[t * 2 + 1] = z;
    }
    short* ph = Ep + (size_t)p * 8192;
    float ss = 0.0f;
    #pragma unroll
    for (int gi = 0; gi < 4; ++gi) {
        int g = gq * 4 + gi;
        f16x8 h;
        f4 av, bv;
        #pragma unroll
        for (int j = 0; j < 8; ++j) {
            float v = E[(size_t)(g * 8 + j) * K_CODES + cp + c];
            h[j] = (_Float16)v;   // RNE cvt
            ss += v * v;
            if (j < 4) av[j] = v; else bv[j - 4] = v;
        }
        *(f16x8*)(ph + (g * 32 + c) * 8) = h;
        *(f4*)(Et32 + (size_t)(cp + c) * D_DIM + g * 8)     = av;
        *(f4*)(Et32 + (size_t)(cp + c) * D_DIM + g * 8 + 4) = bv;
    }
    eepart[gq][c] = ss;
    __syncthreads();
    if (t < 32) {
        float s = 0.0f;
        #pragma unroll
        for (int q = 0; q < 8; ++q) s += eepart[q][t];
        ee[cp + t] = s;
    }
}

// -------- MFMA sieve (R7-frozen loop) + fused merge/flag/gather in pair-finisher --------
// grid 512 = (256 row-tiles x 128 rows) x (2 halves); 2 blocks/CU
__launch_bounds__(256, 2)
__global__ void mfma_sieve_kernel(const float* __restrict__ X,
                                  const short* __restrict__ Ep,
                                  const float* __restrict__ ee,
                                  const float* __restrict__ Et32,
                                  f2* __restrict__ res_bs,     // [row*2+half] = (best, sec)
                                  int* __restrict__ res_idx,   // [row*2+half]
                                  int* __restrict__ ready,     // [256] pair counters
                                  int* __restrict__ counter, int2* __restrict__ list,
                                  float* __restrict__ out, double* __restrict__ loss_sum) {
    __shared__ __align__(16) short Bbuf[2][8192];   // 2 x 16 KB
    __shared__ int bl2_[128];
    __shared__ int do_gather;
    const int t    = threadIdx.x;
    const int w    = t >> 6;
    const int lane = t & 63;
    const int n    = lane & 15;
    const int quad = lane >> 4;
    const int half = blockIdx.x & 1;
    const int rtile = blockIdx.x >> 1;
    const int row0 = rtile * 128;
    const int rw   = row0 + w * 32;
    const int p0   = half * HALF_PANELS;

    // ---- A fragments (32 rows x 256 d) -> fp16 registers ----
    f16x8 Ah[2][8];
    #pragma unroll
    for (int rt = 0; rt < 2; ++rt) {
        const float* xp = X + (size_t)(rw + rt * 16 + n) * D_DIM;
        #pragma unroll
        for (int ks = 0; ks < 8; ++ks) {
            int d = ks * 32 + quad * 8;
            f4 a = *(const f4*)(xp + d);
            f4 b = *(const f4*)(xp + d + 4);
            f16x8 h;
            #pragma unroll
            for (int j = 0; j < 8; ++j) {
                float x = (j < 4) ? a[j] : b[j - 4];
                h[j] = (_Float16)x;
            }
            Ah[rt][ks] = h;
        }
    }

    float bestv[8], secv[8]; int besti[8];
    #pragma unroll
    for (int s = 0; s < 8; ++s) { bestv[s] = 1e30f; secv[s] = 1e30f; besti[s] = 0; }

    {   // prime panel p0 -> buf 0 (16 KB: 4 waves x 4 KB)
        const char* gp = (const char*)Ep + (size_t)p0 * 16384;
        char* lp = (char*)&Bbuf[0][0];
        #pragma unroll
        for (int i = 0; i < 4; ++i)
            gl2lds16(gp + (w * 4 + i) * 1024 + lane * 16, lp + (w * 4 + i) * 1024);
    }
    __syncthreads();

    for (int i = 0; i < HALF_PANELS; ++i) {
        const int p   = p0 + i;
        const int buf = i & 1;
        if (i + 1 < HALF_PANELS) {
            const char* gp = (const char*)Ep + (size_t)(p + 1) * 16384;
            char* lp = (char*)&Bbuf[buf ^ 1][0];
            #pragma unroll
            for (int k = 0; k < 4; ++k)
                gl2lds16(gp + (w * 4 + k) * 1024 + lane * 16, lp + (w * 4 + k) * 1024);
        }

        const short* Bh = &Bbuf[buf][0];

        f32x4 acc[2][2];
        #pragma unroll
        for (int ct = 0; ct < 2; ++ct)
            #pragma unroll
            for (int rt = 0; rt < 2; ++rt)
                acc[ct][rt] = (f32x4)(0.0f);

        #pragma unroll
        for (int ks = 0; ks < 8; ++ks) {
            const int g = ks * 4 + quad;
            f16x8 bh[2];
            #pragma unroll
            for (int ct = 0; ct < 2; ++ct) {
                int c = ct * 16 + n;
                bh[ct] = *(const f16x8*)(Bh + (g * 32 + c) * 8);
            }
            #pragma unroll
            for (int ct = 0; ct < 2; ++ct)
                #pragma unroll
                for (int rt = 0; rt < 2; ++rt)
                    acc[ct][rt] = __builtin_amdgcn_mfma_f32_16x16x32_f16(Ah[rt][ks], bh[ct], acc[ct][rt], 0, 0, 0);
        }

        const int cb = p * 32;
        #pragma unroll
        for (int ct = 0; ct < 2; ++ct) {
            int code = cb + ct * 16 + n;
            float eev = ee[code];
            #pragma unroll
            for (int rt = 0; rt < 2; ++rt)
                #pragma unroll
                for (int r = 0; r < 4; ++r) {
                    float key = fmaf(-2.0f, acc[ct][rt][r], eev);
                    int s = rt * 4 + r;
                    // min/max form; strict-< index semantics preserved
                    float nb = fminf(key, bestv[s]);
                    secv[s]  = fminf(secv[s], fmaxf(key, bestv[s]));
                    besti[s] = (key < bestv[s]) ? code : besti[s];
                    bestv[s] = nb;
                }
        }
        __syncthreads();
    }

    // top-2 merge across the 16 'n' lanes
    #pragma unroll
    for (int off = 1; off < 16; off <<= 1) {
        #pragma unroll
        for (int s = 0; s < 8; ++s) {
            float ov = __shfl_xor(bestv[s], off);
            int   oi = __shfl_xor(besti[s], off);
            float os = __shfl_xor(secv[s], off);
            bool owin = (ov < bestv[s]) || (ov == bestv[s] && oi < besti[s]);
            if (owin) { secv[s] = fminf(os, bestv[s]); bestv[s] = ov; besti[s] = oi; }
            else      { secv[s] = fminf(secv[s], ov); }
        }
    }

    if (n == 0) {
        #pragma unroll
        for (int s = 0; s < 8; ++s) {
            int rl  = w * 32 + (s >> 2) * 16 + quad * 4 + (s & 3);
            int row = row0 + rl;
            f2 bs; bs[0] = bestv[s]; bs[1] = secv[s];
            res_bs[(size_t)row * 2 + half]  = bs;
            res_idx[(size_t)row * 2 + half] = besti[s];
        }
    }

    // ---- pair handshake: second finisher of this row-tile does merge+flag+gather ----
    __threadfence();                 // release our res writes (device scope)
    __syncthreads();
    if (t == 0) {
        int old = atomicAdd(&ready[rtile], 1);
        do_gather = (old == 1);
    }
    __syncthreads();
    if (!do_gather) return;
    __threadfence();                 // acquire the other half's writes

    if (t < 128) {
        const int row = row0 + t;
        union { double d; f2 f; } ua, ub;   // RMW reads (coherence-point, R8-proven)
        ua.d = atomicAdd((double*)&res_bs[(size_t)row * 2], 0.0);
        ub.d = atomicAdd((double*)&res_bs[(size_t)row * 2 + 1], 0.0);
        int ia = atomicOr(&res_idx[(size_t)row * 2], 0);
        int ib = atomicOr(&res_idx[(size_t)row * 2 + 1], 0);
        f2 a = ua.f, b = ub.f;
        float gb; int gi; float gs;
        if (b[0] < a[0]) { gb = b[0]; gi = ib; gs = fminf(b[1], a[0]); }
        else             { gb = a[0]; gi = ia; gs = fminf(a[1], b[0]); }  // tie -> half 0
        bl2_[t] = gi;
        if (gs - gb <= EPS_MARGIN) {
            int pos = atomicAdd(counter, 1);
            if (pos < FB_CAP) list[pos] = make_int2(row, gi);
        }
    }
    __syncthreads();
    double ls = 0.0;
    const int d = t;
    #pragma unroll 4
    for (int r = 0; r < 128; ++r) {
        int code = bl2_[r];
        float q  = Et32[(size_t)code * D_DIM + d];
        float x  = X[(size_t)(row0 + r) * D_DIM + d];
        float dq = q - x;
        out[(size_t)(row0 + r) * D_DIM + d] = x + dq;
        ls += (double)dq * (double)dq;
    }
    #pragma unroll
    for (int off = 32; off > 0; off >>= 1)
        ls += __shfl_down(ls, off);
    if ((t & 63) == 0) atomicAdd(loss_sum, ls);
}

// -------- refine phase 1: fp64 keys, 16 rows/chunk x 32 slices of 256 codes --------
__global__ void refine1_kernel(const float* __restrict__ X, const float* __restrict__ E,
                               const int* __restrict__ counter, const int2* __restrict__ list,
                               double* __restrict__ res_v, int* __restrict__ res_i) {
    __shared__ double xt[FB_RPB][D_DIM];   // 32 KB
    __shared__ int rows_sh[FB_RPB];
    __shared__ double wbv[4][FB_RPB];
    __shared__ int    wbi[4][FB_RPB];

    int nf = *counter; if (nf > FB_CAP) nf = FB_CAP;
    const int nchunks = (nf + FB_RPB - 1) / FB_RPB;
    const int nitems  = nchunks * RF_SLICES;
    const int t = threadIdx.x;

    for (int item = blockIdx.x; item < nitems; item += gridDim.x) {
        const int rc = item / RF_SLICES;
        const int sl = item % RF_SLICES;
        __syncthreads();
        if (t < FB_RPB) {
            int e = rc * FB_RPB + t;
            int2 ent = list[(e < nf) ? e : 0];
            rows_sh[t] = ent.x;
        }
        __syncthreads();
        #pragma unroll
        for (int j = 0; j < FB_RPB; ++j)
            xt[j][t] = (double)X[(size_t)rows_sh[j] * D_DIM + t];
        __syncthreads();

        const int k0 = sl * 256 + t;       // one code per thread
        double s[FB_RPB], q = 0.0;
        #pragma unroll
        for (int j = 0; j < FB_RPB; ++j) s[j] = 0.0;
        for (int d = 0; d < D_DIM; ++d) {
            double e0d = (double)E[(size_t)d * K_CODES + k0];
            q += e0d * e0d;
            #pragma unroll
            for (int j = 0; j < FB_RPB; ++j)
                s[j] += xt[j][d] * e0d;
        }
        double bv[FB_RPB]; int bi[FB_RPB];
        #pragma unroll
        for (int j = 0; j < FB_RPB; ++j) { bv[j] = q - 2.0 * s[j]; bi[j] = k0; }
        #pragma unroll
        for (int off = 1; off < 64; off <<= 1) {
            #pragma unroll
            for (int j = 0; j < FB_RPB; ++j) {
                double ov = __shfl_xor(bv[j], off);
                int    oi = __shfl_xor(bi[j], off);
                if (ov < bv[j] || (ov == bv[j] && oi < bi[j])) { bv[j] = ov; bi[j] = oi; }
            }
        }
        const int wave = t >> 6;
        if ((t & 63) == 0) {
            #pragma unroll
            for (int j = 0; j < FB_RPB; ++j) { wbv[wave][j] = bv[j]; wbi[wave][j] = bi[j]; }
        }
        __syncthreads();
        if (t < FB_RPB) {
            double b = wbv[0][t]; int i_ = wbi[0][t];
            #pragma unroll
            for (int wv = 1; wv < 4; ++wv) {
                double ov = wbv[wv][t]; int oi = wbi[wv][t];
                if (ov < b || (ov == b && oi < i_)) { b = ov; i_ = oi; }
            }
            int e = rc * FB_RPB + t;
            res_v[(size_t)e * RF_SLICES + sl] = b;
            res_i[(size_t)e * RF_SLICES + sl] = i_;
        }
    }
}

// -------- refine phase 2: pick fp64 winner, patch row + loss; last block emits fin --------
__global__ void patch_kernel(const float* __restrict__ X, const float* __restrict__ Et32,
                             float* __restrict__ out, double* __restrict__ loss_sum,
                             const int* __restrict__ counter, const int2* __restrict__ list,
                             const double* __restrict__ res_v, const int* __restrict__ res_i,
                             int* __restrict__ patch_done) {
    int nf = *counter; if (nf > FB_CAP) nf = FB_CAP;
    __shared__ int nc_sh;
    const int t = threadIdx.x;
    for (int b = blockIdx.x; b < nf; b += gridDim.x) {
        __syncthreads();
        if (t == 0) {
            double bv = res_v[(size_t)b * RF_SLICES]; int bi = res_i[(size_t)b * RF_SLICES];
            for (int s = 1; s < RF_SLICES; ++s) {
                double v = res_v[(size_t)b * RF_SLICES + s];
                int    i = res_i[(size_t)b * RF_SLICES + s];
                if (v < bv || (v == bv && i < bi)) { bv = v; bi = i; }
            }
            nc_sh = bi;
        }
        __syncthreads();
        int2 ent = list[b];
        const int oc = ent.y, row = ent.x, nc = nc_sh;
        if (nc != oc) {       // uniform branch across block
            float x  = X[(size_t)row * D_DIM + t];
            float qn = Et32[(size_t)nc * D_DIM + t];
            float qo = Et32[(size_t)oc * D_DIM + t];
            float dqn = qn - x, dqo = qo - x;
            out[(size_t)row * D_DIM + t] = x + dqn;
            double dl = (double)dqn * dqn - (double)dqo * dqo;
            #pragma unroll
            for (int off = 32; off > 0; off >>= 1)
                dl += __shfl_down(dl, off);
            if ((t & 63) == 0) atomicAdd(loss_sum, dl);
        }
    }
    // ---- fin: last block to finish reads total loss and writes the scalar ----
    __threadfence();                 // release our loss adds before the counter bump
    __syncthreads();
    if (t == 0) {
        int old = atomicAdd(patch_done, 1);
        if (old == (int)gridDim.x - 1) {
            double m = atomicAdd(loss_sum, 0.0) / (double)NUM_ELEM;   // RMW read
            out[NUM_ELEM] = (float)(0.25 * m + m);
        }
    }
}

extern "C" void kernel_launch(void* const* d_in, const int* in_sizes, int n_in,
                              void* d_out, int out_size, void* d_ws, size_t ws_size,
                              hipStream_t stream) {
    const float* X = (const float*)d_in[0];   // [32,1024,256] fp32
    const float* E = (const float*)d_in[1];   // [256,8192] fp32
    float* out = (float*)d_out;

    // ws layout (ctl region [0,8192) zeroed by prep block 0)
    double* loss_sum   = (double*)d_ws;                        // @0 (8 B)
    int*    counter    = (int*)((char*)d_ws + 8);              // @8
    int*    patch_done = (int*)((char*)d_ws + 16);             // @16
    int*    ready      = (int*)((char*)d_ws + 1024);           // @1024 (256 ints)
    float*  ee         = (float*)((char*)d_ws + 8192);         // 32 KB
    int2*   list       = (int2*)((char*)d_ws + 40960);         // 64 KB
    double* res_v      = (double*)((char*)d_ws + 131072);      // 2 MB (8192 x 32 x 8B)
    int*    res_i      = (int*)((char*)d_ws + 2228224);        // 1 MB
    float*  Et32       = (float*)((char*)d_ws + 4194304);      // 8 MB
    short*  Ep         = (short*)((char*)d_ws + 12582912);     // 4 MB
    f2*     res_bs     = (f2*)((char*)d_ws + 16777216);        // 512 KB
    int*    res_idx    = (int*)((char*)d_ws + 17301504);       // 256 KB

    prep_kernel<<<N_PANELS, 256, 0, stream>>>(E, Ep, Et32, ee, (float*)d_ws);
    mfma_sieve_kernel<<<512, 256, 0, stream>>>(X, Ep, ee, Et32, res_bs, res_idx,
                                               ready, counter, list, out, loss_sum);
    refine1_kernel<<<1024, 256, 0, stream>>>(X, E, counter, list, res_v, res_i);
    patch_kernel<<<1024, 256, 0, stream>>>(X, Et32, out, loss_sum, counter, list,
                                           res_v, res_i, patch_done);
}

// Round 11
// 399.731 us; speedup vs baseline: 1.2602x; 1.2602x over previous
//
#include <hip/hip_runtime.h>

typedef float f4   __attribute__((ext_vector_type(4)));
typedef float f2   __attribute__((ext_vector_type(2)));
typedef _Float16 f16x8 __attribute__((ext_vector_type(8)));
typedef float f32x4  __attribute__((ext_vector_type(4)));

#define N_ROWS  32768
#define D_DIM   256
#define K_CODES 8192
#define NUM_ELEM (N_ROWS * D_DIM)
#define EPS_MARGIN 2e-3f     // fp16 single-pass sieve: key-diff err sigma ~2.6e-4 -> 7.7 sigma
#define FB_CAP  8192
#define FB_RPB  16           // rows per refine chunk
#define RF_SLICES 32         // code slices of 256
#define N_PANELS 256         // 32 codes per panel
#define QTR_PANELS 64        // panels per code-quarter (4 parts)

__device__ __forceinline__ void gl2lds16(const void* g, void* l) {
    __builtin_amdgcn_global_load_lds(
        (const __attribute__((address_space(1))) unsigned int*)g,
        (__attribute__((address_space(3))) unsigned int*)l, 16, 0, 0);
}

// -------- fused prep: ctl-zero + Ep (panel-major fp16) + Et32 (E^T fp32) + ee --------
__global__ void prep_kernel(const float* __restrict__ E, short* __restrict__ Ep,
                            float* __restrict__ Et32, float* __restrict__ ee,
                            float* __restrict__ ctl) {
    __shared__ float eepart[8][32];
    const int p  = blockIdx.x;
    const int t  = threadIdx.x;
    const int c  = t & 31;
    const int gq = t >> 5;
    const int cp = p * 32;
    if (p == 0) {   // zero control region [0, 8192): loss_sum, counter, patch_done
        f4 z = (f4)(0.0f);
        f4* dst = (f4*)ctl;
        dst[t * 2]     = z;
        dst[t * 2 + 1] = z;
    }
    short* ph = Ep + (size_t)p * 8192;
    float ss = 0.0f;
    #pragma unroll
    for (int gi = 0; gi < 4; ++gi) {
        int g = gq * 4 + gi;
        f16x8 h;
        f4 av, bv;
        #pragma unroll
        for (int j = 0; j < 8; ++j) {
            float v = E[(size_t)(g * 8 + j) * K_CODES + cp + c];
            h[j] = (_Float16)v;   // RNE cvt
            ss += v * v;
            if (j < 4) av[j] = v; else bv[j - 4] = v;
        }
        *(f16x8*)(ph + (g * 32 + c) * 8) = h;
        *(f4*)(Et32 + (size_t)(cp + c) * D_DIM + g * 8)     = av;
        *(f4*)(Et32 + (size_t)(cp + c) * D_DIM + g * 8 + 4) = bv;
    }
    eepart[gq][c] = ss;
    __syncthreads();
    if (t < 32) {
        float s = 0.0f;
        #pragma unroll
        for (int q = 0; q < 8; ++q) s += eepart[q][t];
        ee[cp + t] = s;
    }
}

// -------- MFMA sieve: R1-exact datapath x 4 K-quarters for TLP --------
// grid 1024 = (256 row-tiles x 128 rows) x (4 quarters); 32 KB LDS -> 4 blocks/CU
__launch_bounds__(256, 2)
__global__ void mfma_sieve_kernel(const float* __restrict__ X,
                                  const short* __restrict__ Ep,
                                  const float* __restrict__ ee,
                                  f2* __restrict__ res_bs,     // [row*4+part] = (best, sec)
                                  int* __restrict__ res_idx) { // [row*4+part]
    __shared__ __align__(16) short Bbuf[2][8192];   // 2 x 16 KB
    const int t    = threadIdx.x;
    const int w    = t >> 6;
    const int lane = t & 63;
    const int n    = lane & 15;
    const int quad = lane >> 4;
    const int part = blockIdx.x & 3;
    const int row0 = (blockIdx.x >> 2) * 128;
    const int rw   = row0 + w * 32;
    const int p0   = part * QTR_PANELS;

    // ---- A fragments (32 rows x 256 d) -> fp16 registers ----
    f16x8 Ah[2][8];
    #pragma unroll
    for (int rt = 0; rt < 2; ++rt) {
        const float* xp = X + (size_t)(rw + rt * 16 + n) * D_DIM;
        #pragma unroll
        for (int ks = 0; ks < 8; ++ks) {
            int d = ks * 32 + quad * 8;
            f4 a = *(const f4*)(xp + d);
            f4 b = *(const f4*)(xp + d + 4);
            f16x8 h;
            #pragma unroll
            for (int j = 0; j < 8; ++j) {
                float x = (j < 4) ? a[j] : b[j - 4];
                h[j] = (_Float16)x;
            }
            Ah[rt][ks] = h;
        }
    }

    float bestv[8], secv[8]; int besti[8];
    #pragma unroll
    for (int s = 0; s < 8; ++s) { bestv[s] = 1e30f; secv[s] = 1e30f; besti[s] = 0; }

    {   // prime panel p0 -> buf 0 (16 KB: 4 waves x 4 KB)
        const char* gp = (const char*)Ep + (size_t)p0 * 16384;
        char* lp = (char*)&Bbuf[0][0];
        #pragma unroll
        for (int i = 0; i < 4; ++i)
            gl2lds16(gp + (w * 4 + i) * 1024 + lane * 16, lp + (w * 4 + i) * 1024);
    }
    __syncthreads();

    for (int i = 0; i < QTR_PANELS; ++i) {
        const int p   = p0 + i;
        const int buf = i & 1;
        if (i + 1 < QTR_PANELS) {
            const char* gp = (const char*)Ep + (size_t)(p + 1) * 16384;
            char* lp = (char*)&Bbuf[buf ^ 1][0];
            #pragma unroll
            for (int k = 0; k < 4; ++k)
                gl2lds16(gp + (w * 4 + k) * 1024 + lane * 16, lp + (w * 4 + k) * 1024);
        }

        const short* Bh = &Bbuf[buf][0];

        f32x4 acc[2][2];
        #pragma unroll
        for (int ct = 0; ct < 2; ++ct)
            #pragma unroll
            for (int rt = 0; rt < 2; ++rt)
                acc[ct][rt] = (f32x4)(0.0f);

        #pragma unroll
        for (int ks = 0; ks < 8; ++ks) {
            const int g = ks * 4 + quad;
            f16x8 bh[2];
            #pragma unroll
            for (int ct = 0; ct < 2; ++ct) {
                int c = ct * 16 + n;
                bh[ct] = *(const f16x8*)(Bh + (g * 32 + c) * 8);
            }
            #pragma unroll
            for (int ct = 0; ct < 2; ++ct)
                #pragma unroll
                for (int rt = 0; rt < 2; ++rt)
                    acc[ct][rt] = __builtin_amdgcn_mfma_f32_16x16x32_f16(Ah[rt][ks], bh[ct], acc[ct][rt], 0, 0, 0);
        }

        const int cb = p * 32;
        #pragma unroll
        for (int ct = 0; ct < 2; ++ct) {
            int code = cb + ct * 16 + n;
            float eev = ee[code];
            #pragma unroll
            for (int rt = 0; rt < 2; ++rt)
                #pragma unroll
                for (int r = 0; r < 4; ++r) {
                    float key = fmaf(-2.0f, acc[ct][rt][r], eev);
                    int s = rt * 4 + r;
                    // min/max form; strict-< index semantics preserved
                    float nb = fminf(key, bestv[s]);
                    secv[s]  = fminf(secv[s], fmaxf(key, bestv[s]));
                    besti[s] = (key < bestv[s]) ? code : besti[s];
                    bestv[s] = nb;
                }
        }
        __syncthreads();
    }

    // top-2 merge across the 16 'n' lanes
    #pragma unroll
    for (int off = 1; off < 16; off <<= 1) {
        #pragma unroll
        for (int s = 0; s < 8; ++s) {
            float ov = __shfl_xor(bestv[s], off);
            int   oi = __shfl_xor(besti[s], off);
            float os = __shfl_xor(secv[s], off);
            bool owin = (ov < bestv[s]) || (ov == bestv[s] && oi < besti[s]);
            if (owin) { secv[s] = fminf(os, bestv[s]); bestv[s] = ov; besti[s] = oi; }
            else      { secv[s] = fminf(secv[s], ov); }
        }
    }

    if (n == 0) {
        #pragma unroll
        for (int s = 0; s < 8; ++s) {
            int rl  = w * 32 + (s >> 2) * 16 + quad * 4 + (s & 3);
            int row = row0 + rl;
            f2 bs; bs[0] = bestv[s]; bs[1] = secv[s];
            res_bs[(size_t)row * 4 + part]  = bs;
            res_idx[(size_t)row * 4 + part] = besti[s];
        }
    }
}

// -------- fused merge(4 quarters)+flag + gather + straight-through output + loss --------
__global__ void gather_kernel(const float* __restrict__ X, const float* __restrict__ Et32,
                              const f2* __restrict__ res_bs, const int* __restrict__ res_idx,
                              int* __restrict__ counter, int2* __restrict__ list,
                              float* __restrict__ out, double* __restrict__ loss_sum) {
    __shared__ int bl_[128];
    const int t    = threadIdx.x;
    const int row0 = blockIdx.x * 128;
    if (t < 128) {
        const int row = row0 + t;
        float gb = 1e30f, gs = 1e30f; int gi = 0;
        #pragma unroll
        for (int p = 0; p < 4; ++p) {     // ascending code order -> lowest-idx tie keeps first
            f2 v  = res_bs[(size_t)row * 4 + p];
            int vi = res_idx[(size_t)row * 4 + p];
            if (v[0] < gb) { gs = fminf(gb, v[1]); gb = v[0]; gi = vi; }
            else           { gs = fminf(gs, v[0]); }
        }
        bl_[t] = gi;
        if (gs - gb <= EPS_MARGIN) {
            int pos = atomicAdd(counter, 1);
            if (pos < FB_CAP) list[pos] = make_int2(row, gi);
        }
    }
    __syncthreads();
    double ls = 0.0;
    const int d = t;
    #pragma unroll 4
    for (int r = 0; r < 128; ++r) {
        int code = bl_[r];
        float q  = Et32[(size_t)code * D_DIM + d];
        float x  = X[(size_t)(row0 + r) * D_DIM + d];
        float dq = q - x;
        out[(size_t)(row0 + r) * D_DIM + d] = x + dq;
        ls += (double)dq * (double)dq;
    }
    #pragma unroll
    for (int off = 32; off > 0; off >>= 1)
        ls += __shfl_down(ls, off);
    if ((t & 63) == 0) atomicAdd(loss_sum, ls);
}

// -------- refine phase 1: fp64 keys, 16 rows/chunk x 32 slices of 256 codes --------
__global__ void refine1_kernel(const float* __restrict__ X, const float* __restrict__ E,
                               const int* __restrict__ counter, const int2* __restrict__ list,
                               double* __restrict__ res_v, int* __restrict__ res_i) {
    __shared__ double xt[FB_RPB][D_DIM];   // 32 KB
    __shared__ int rows_sh[FB_RPB];
    __shared__ double wbv[4][FB_RPB];
    __shared__ int    wbi[4][FB_RPB];

    int nf = *counter; if (nf > FB_CAP) nf = FB_CAP;
    const int nchunks = (nf + FB_RPB - 1) / FB_RPB;
    const int nitems  = nchunks * RF_SLICES;
    const int t = threadIdx.x;

    for (int item = blockIdx.x; item < nitems; item += gridDim.x) {
        const int rc = item / RF_SLICES;
        const int sl = item % RF_SLICES;
        __syncthreads();
        if (t < FB_RPB) {
            int e = rc * FB_RPB + t;
            int2 ent = list[(e < nf) ? e : 0];
            rows_sh[t] = ent.x;
        }
        __syncthreads();
        #pragma unroll
        for (int j = 0; j < FB_RPB; ++j)
            xt[j][t] = (double)X[(size_t)rows_sh[j] * D_DIM + t];
        __syncthreads();

        const int k0 = sl * 256 + t;       // one code per thread
        double s[FB_RPB], q = 0.0;
        #pragma unroll
        for (int j = 0; j < FB_RPB; ++j) s[j] = 0.0;
        for (int d = 0; d < D_DIM; ++d) {
            double e0d = (double)E[(size_t)d * K_CODES + k0];
            q += e0d * e0d;
            #pragma unroll
            for (int j = 0; j < FB_RPB; ++j)
                s[j] += xt[j][d] * e0d;
        }
        double bv[FB_RPB]; int bi[FB_RPB];
        #pragma unroll
        for (int j = 0; j < FB_RPB; ++j) { bv[j] = q - 2.0 * s[j]; bi[j] = k0; }
        #pragma unroll
        for (int off = 1; off < 64; off <<= 1) {
            #pragma unroll
            for (int j = 0; j < FB_RPB; ++j) {
                double ov = __shfl_xor(bv[j], off);
                int    oi = __shfl_xor(bi[j], off);
                if (ov < bv[j] || (ov == bv[j] && oi < bi[j])) { bv[j] = ov; bi[j] = oi; }
            }
        }
        const int wave = t >> 6;
        if ((t & 63) == 0) {
            #pragma unroll
            for (int j = 0; j < FB_RPB; ++j) { wbv[wave][j] = bv[j]; wbi[wave][j] = bi[j]; }
        }
        __syncthreads();
        if (t < FB_RPB) {
            double b = wbv[0][t]; int i_ = wbi[0][t];
            #pragma unroll
            for (int wv = 1; wv < 4; ++wv) {
                double ov = wbv[wv][t]; int oi = wbi[wv][t];
                if (ov < b || (ov == b && oi < i_)) { b = ov; i_ = oi; }
            }
            int e = rc * FB_RPB + t;
            res_v[(size_t)e * RF_SLICES + sl] = b;
            res_i[(size_t)e * RF_SLICES + sl] = i_;
        }
    }
}

// -------- refine phase 2: pick fp64 winner, patch row + loss; last block emits fin --------
__global__ void patch_kernel(const float* __restrict__ X, const float* __restrict__ Et32,
                             float* __restrict__ out, double* __restrict__ loss_sum,
                             const int* __restrict__ counter, const int2* __restrict__ list,
                             const double* __restrict__ res_v, const int* __restrict__ res_i,
                             int* __restrict__ patch_done) {
    int nf = *counter; if (nf > FB_CAP) nf = FB_CAP;
    __shared__ int nc_sh;
    const int t = threadIdx.x;
    for (int b = blockIdx.x; b < nf; b += gridDim.x) {
        __syncthreads();
        if (t == 0) {
            double bv = res_v[(size_t)b * RF_SLICES]; int bi = res_i[(size_t)b * RF_SLICES];
            for (int s = 1; s < RF_SLICES; ++s) {
                double v = res_v[(size_t)b * RF_SLICES + s];
                int    i = res_i[(size_t)b * RF_SLICES + s];
                if (v < bv || (v == bv && i < bi)) { bv = v; bi = i; }
            }
            nc_sh = bi;
        }
        __syncthreads();
        int2 ent = list[b];
        const int oc = ent.y, row = ent.x, nc = nc_sh;
        if (nc != oc) {       // uniform branch across block
            float x  = X[(size_t)row * D_DIM + t];
            float qn = Et32[(size_t)nc * D_DIM + t];
            float qo = Et32[(size_t)oc * D_DIM + t];
            float dqn = qn - x, dqo = qo - x;
            out[(size_t)row * D_DIM + t] = x + dqn;
            double dl = (double)dqn * dqn - (double)dqo * dqo;
            #pragma unroll
            for (int off = 32; off > 0; off >>= 1)
                dl += __shfl_down(dl, off);
            if ((t & 63) == 0) atomicAdd(loss_sum, dl);
        }
    }
    // ---- fin: last block to finish reads total loss and writes the scalar ----
    __threadfence();                 // release our loss adds before the counter bump
    __syncthreads();
    if (t == 0) {
        int old = atomicAdd(patch_done, 1);
        if (old == (int)gridDim.x - 1) {
            double m = atomicAdd(loss_sum, 0.0) / (double)NUM_ELEM;   // RMW read
            out[NUM_ELEM] = (float)(0.25 * m + m);
        }
    }
}

extern "C" void kernel_launch(void* const* d_in, const int* in_sizes, int n_in,
                              void* d_out, int out_size, void* d_ws, size_t ws_size,
                              hipStream_t stream) {
    const float* X = (const float*)d_in[0];   // [32,1024,256] fp32
    const float* E = (const float*)d_in[1];   // [256,8192] fp32
    float* out = (float*)d_out;

    // ws layout (ctl region [0,8192) zeroed by prep block 0)
    double* loss_sum   = (double*)d_ws;                        // @0 (8 B)
    int*    counter    = (int*)((char*)d_ws + 8);              // @8
    int*    patch_done = (int*)((char*)d_ws + 16);             // @16
    float*  ee         = (float*)((char*)d_ws + 8192);         // 32 KB
    int2*   list       = (int2*)((char*)d_ws + 40960);         // 64 KB
    double* res_v      = (double*)((char*)d_ws + 131072);      // 2 MB (8192 x 32 x 8B)
    int*    res_i      = (int*)((char*)d_ws + 2228224);        // 1 MB
    float*  Et32       = (float*)((char*)d_ws + 4194304);      // 8 MB
    short*  Ep         = (short*)((char*)d_ws + 12582912);     // 4 MB
    f2*     res_bs     = (f2*)((char*)d_ws + 16777216);        // 1 MB (131072 x f2)
    int*    res_idx    = (int*)((char*)d_ws + 17825792);       // 512 KB

    prep_kernel<<<N_PANELS, 256, 0, stream>>>(E, Ep, Et32, ee, (float*)d_ws);
    mfma_sieve_kernel<<<1024, 256, 0, stream>>>(X, Ep, ee, res_bs, res_idx);
    gather_kernel<<<N_ROWS / 128, 256, 0, stream>>>(X, Et32, res_bs, res_idx,
                                                    counter, list, out, loss_sum);
    refine1_kernel<<<1024, 256, 0, stream>>>(X, E, counter, list, res_v, res_i);
    patch_kernel<<<1024, 256, 0, stream>>>(X, Et32, out, loss_sum, counter, list,
                                           res_v, res_i, patch_done);
}

// Round 12
// 383.445 us; speedup vs baseline: 1.3137x; 1.0425x over previous
//
#include <hip/hip_runtime.h>

typedef float f4   __attribute__((ext_vector_type(4)));
typedef float f2   __attribute__((ext_vector_type(2)));
typedef _Float16 f16x8 __attribute__((ext_vector_type(8)));
typedef float f32x4  __attribute__((ext_vector_type(4)));

#define N_ROWS  32768
#define D_DIM   256
#define K_CODES 8192
#define NUM_ELEM (N_ROWS * D_DIM)
#define EPS_MARGIN 2e-3f     // fp16 single-pass sieve: key-diff err sigma ~2.6e-4 -> 7.7 sigma
#define FB_CAP  8192
#define FB_RPB  8
#define RF_SLICES 16
#define N_PANELS 256         // 32 codes per panel
#define HALF_PANELS 128      // panels per code-half
#define HALF_PAIRS 64        // panel-pairs per half (2 panels per barrier)

__device__ __forceinline__ void gl2lds16(const void* g, void* l) {
    __builtin_amdgcn_global_load_lds(
        (const __attribute__((address_space(1))) unsigned int*)g,
        (__attribute__((address_space(3))) unsigned int*)l, 16, 0, 0);
}

// -------- fused prep: ctl-zero + Ep (panel-major fp16) + Et32 (E^T fp32) + ee --------
__global__ void prep_kernel(const float* __restrict__ E, short* __restrict__ Ep,
                            float* __restrict__ Et32, float* __restrict__ ee,
                            float* __restrict__ ctl) {
    __shared__ float eepart[8][32];
    const int p  = blockIdx.x;
    const int t  = threadIdx.x;
    const int c  = t & 31;
    const int gq = t >> 5;
    const int cp = p * 32;
    if (p == 0) {   // zero control region [0, 8192): loss_sum, counter, patch_done
        f4 z = (f4)(0.0f);
        f4* dst = (f4*)ctl;
        dst[t * 2]     = z;
        dst[t * 2 + 1] = z;
    }
    short* ph = Ep + (size_t)p * 8192;
    float ss = 0.0f;
    #pragma unroll
    for (int gi = 0; gi < 4; ++gi) {
        int g = gq * 4 + gi;
        f16x8 h;
        f4 av, bv;
        #pragma unroll
        for (int j = 0; j < 8; ++j) {
            float v = E[(size_t)(g * 8 + j) * K_CODES + cp + c];
            h[j] = (_Float16)v;   // RNE cvt
            ss += v * v;
            if (j < 4) av[j] = v; else bv[j - 4] = v;
        }
        *(f16x8*)(ph + (g * 32 + c) * 8) = h;
        *(f4*)(Et32 + (size_t)(cp + c) * D_DIM + g * 8)     = av;
        *(f4*)(Et32 + (size_t)(cp + c) * D_DIM + g * 8 + 4) = bv;
    }
    eepart[gq][c] = ss;
    __syncthreads();
    if (t < 32) {
        float s = 0.0f;
        #pragma unroll
        for (int q = 0; q < 8; ++q) s += eepart[q][t];
        ee[cp + t] = s;
    }
}

// -------- MFMA sieve: R7-frozen datapath, 2 panels per barrier (drain amortization) --------
// grid 512 = (256 row-tiles x 128 rows) x (2 halves); 64 KB LDS -> 2 blocks/CU
__launch_bounds__(256, 2)
__global__ void mfma_sieve_kernel(const float* __restrict__ X,
                                  const short* __restrict__ Ep,
                                  const float* __restrict__ ee,
                                  f2* __restrict__ res_bs,     // [row*2+half] = (best, sec)
                                  int* __restrict__ res_idx) { // [row*2+half]
    __shared__ __align__(16) short Bbuf[2][16384];  // 2 pair-buffers x 32 KB
    const int t    = threadIdx.x;
    const int w    = t >> 6;
    const int lane = t & 63;
    const int n    = lane & 15;
    const int quad = lane >> 4;
    const int half = blockIdx.x & 1;
    const int row0 = (blockIdx.x >> 1) * 128;
    const int rw   = row0 + w * 32;
    const int p0   = half * HALF_PANELS;

    // ---- A fragments (32 rows x 256 d) -> fp16 registers ----
    f16x8 Ah[2][8];
    #pragma unroll
    for (int rt = 0; rt < 2; ++rt) {
        const float* xp = X + (size_t)(rw + rt * 16 + n) * D_DIM;
        #pragma unroll
        for (int ks = 0; ks < 8; ++ks) {
            int d = ks * 32 + quad * 8;
            f4 a = *(const f4*)(xp + d);
            f4 b = *(const f4*)(xp + d + 4);
            f16x8 h;
            #pragma unroll
            for (int j = 0; j < 8; ++j) {
                float x = (j < 4) ? a[j] : b[j - 4];
                h[j] = (_Float16)x;
            }
            Ah[rt][ks] = h;
        }
    }

    float bestv[8], secv[8]; int besti[8];
    #pragma unroll
    for (int s = 0; s < 8; ++s) { bestv[s] = 1e30f; secv[s] = 1e30f; besti[s] = 0; }

    {   // prime pair 0 (panels p0, p0+1) -> Bbuf[0] (32 KB: 8 gl2lds per wave)
        const char* gp = (const char*)Ep + (size_t)p0 * 16384;
        char* lp = (char*)&Bbuf[0][0];
        #pragma unroll
        for (int i = 0; i < 8; ++i)
            gl2lds16(gp + (w * 8 + i) * 1024 + lane * 16, lp + (w * 8 + i) * 1024);
    }
    __syncthreads();

    for (int ii = 0; ii < HALF_PAIRS; ++ii) {
        const int pbuf = ii & 1;
        if (ii + 1 < HALF_PAIRS) {   // prefetch next pair (32 KB)
            const char* gp = (const char*)Ep + (size_t)(p0 + 2 * (ii + 1)) * 16384;
            char* lp = (char*)&Bbuf[pbuf ^ 1][0];
            #pragma unroll
            for (int k = 0; k < 8; ++k)
                gl2lds16(gp + (w * 8 + k) * 1024 + lane * 16, lp + (w * 8 + k) * 1024);
        }

        #pragma unroll
        for (int sub = 0; sub < 2; ++sub) {
            const int p = p0 + 2 * ii + sub;
            const short* Bh = &Bbuf[pbuf][sub * 8192];

            f32x4 acc[2][2];
            #pragma unroll
            for (int ct = 0; ct < 2; ++ct)
                #pragma unroll
                for (int rt = 0; rt < 2; ++rt)
                    acc[ct][rt] = (f32x4)(0.0f);

            #pragma unroll
            for (int ks = 0; ks < 8; ++ks) {
                const int g = ks * 4 + quad;
                f16x8 bh[2];
                #pragma unroll
                for (int ct = 0; ct < 2; ++ct) {
                    int c = ct * 16 + n;
                    bh[ct] = *(const f16x8*)(Bh + (g * 32 + c) * 8);
                }
                #pragma unroll
                for (int ct = 0; ct < 2; ++ct)
                    #pragma unroll
                    for (int rt = 0; rt < 2; ++rt)
                        acc[ct][rt] = __builtin_amdgcn_mfma_f32_16x16x32_f16(Ah[rt][ks], bh[ct], acc[ct][rt], 0, 0, 0);
            }

            const int cb = p * 32;
            #pragma unroll
            for (int ct = 0; ct < 2; ++ct) {
                int code = cb + ct * 16 + n;
                float eev = ee[code];
                #pragma unroll
                for (int rt = 0; rt < 2; ++rt)
                    #pragma unroll
                    for (int r = 0; r < 4; ++r) {
                        float key = fmaf(-2.0f, acc[ct][rt][r], eev);
                        int s = rt * 4 + r;
                        // min/max form; strict-< index semantics preserved
                        float nb = fminf(key, bestv[s]);
                        secv[s]  = fminf(secv[s], fmaxf(key, bestv[s]));
                        besti[s] = (key < bestv[s]) ? code : besti[s];
                        bestv[s] = nb;
                    }
            }
        }
        __syncthreads();   // one barrier per 2 panels
    }

    // top-2 merge across the 16 'n' lanes
    #pragma unroll
    for (int off = 1; off < 16; off <<= 1) {
        #pragma unroll
        for (int s = 0; s < 8; ++s) {
            float ov = __shfl_xor(bestv[s], off);
            int   oi = __shfl_xor(besti[s], off);
            float os = __shfl_xor(secv[s], off);
            bool owin = (ov < bestv[s]) || (ov == bestv[s] && oi < besti[s]);
            if (owin) { secv[s] = fminf(os, bestv[s]); bestv[s] = ov; besti[s] = oi; }
            else      { secv[s] = fminf(secv[s], ov); }
        }
    }

    if (n == 0) {
        #pragma unroll
        for (int s = 0; s < 8; ++s) {
            int rl  = w * 32 + (s >> 2) * 16 + quad * 4 + (s & 3);
            int row = row0 + rl;
            f2 bs; bs[0] = bestv[s]; bs[1] = secv[s];
            res_bs[(size_t)row * 2 + half]  = bs;
            res_idx[(size_t)row * 2 + half] = besti[s];
        }
    }
}

// -------- fused merge(2 halves)+flag + gather + straight-through output + loss --------
__global__ void gather_kernel(const float* __restrict__ X, const float* __restrict__ Et32,
                              const f2* __restrict__ res_bs, const int* __restrict__ res_idx,
                              int* __restrict__ counter, int2* __restrict__ list,
                              float* __restrict__ out, double* __restrict__ loss_sum) {
    __shared__ int bl_[128];
    const int t    = threadIdx.x;
    const int row0 = blockIdx.x * 128;
    if (t < 128) {
        const int row = row0 + t;
        f2 a = res_bs[(size_t)row * 2];      // half 0 (indices < half 1's)
        f2 b = res_bs[(size_t)row * 2 + 1];
        int ia = res_idx[(size_t)row * 2];
        int ib = res_idx[(size_t)row * 2 + 1];
        float gb; int gi; float gs;
        if (b[0] < a[0]) { gb = b[0]; gi = ib; gs = fminf(b[1], a[0]); }
        else             { gb = a[0]; gi = ia; gs = fminf(a[1], b[0]); }  // tie -> half 0 (lower idx)
        bl_[t] = gi;
        if (gs - gb <= EPS_MARGIN) {
            int pos = atomicAdd(counter, 1);
            if (pos < FB_CAP) list[pos] = make_int2(row, gi);
        }
    }
    __syncthreads();
    double ls = 0.0;
    const int d = t;
    #pragma unroll 4
    for (int r = 0; r < 128; ++r) {
        int code = bl_[r];
        float q  = Et32[(size_t)code * D_DIM + d];
        float x  = X[(size_t)(row0 + r) * D_DIM + d];
        float dq = q - x;
        out[(size_t)(row0 + r) * D_DIM + d] = x + dq;
        ls += (double)dq * (double)dq;
    }
    #pragma unroll
    for (int off = 32; off > 0; off >>= 1)
        ls += __shfl_down(ls, off);
    if ((t & 63) == 0) atomicAdd(loss_sum, ls);
}

// -------- refine phase 1: fp64 keys over (row-chunk x 16 slices) --------
__global__ void refine1_kernel(const float* __restrict__ X, const float* __restrict__ E,
                               const int* __restrict__ counter, const int2* __restrict__ list,
                               double* __restrict__ res_v, int* __restrict__ res_i) {
    __shared__ float xt[D_DIM][FB_RPB];
    __shared__ int rows_sh[FB_RPB];
    __shared__ double wbv[4][FB_RPB];
    __shared__ int    wbi[4][FB_RPB];

    int nf = *counter; if (nf > FB_CAP) nf = FB_CAP;
    const int nchunks = (nf + FB_RPB - 1) / FB_RPB;
    const int nitems  = nchunks * RF_SLICES;
    const int t = threadIdx.x;

    for (int item = blockIdx.x; item < nitems; item += gridDim.x) {
        const int rc = item / RF_SLICES;
        const int sl = item % RF_SLICES;
        __syncthreads();
        if (t < FB_RPB) {
            int e = rc * FB_RPB + t;
            int2 ent = list[(e < nf) ? e : 0];
            rows_sh[t] = ent.x;
        }
        __syncthreads();
        #pragma unroll
        for (int j = 0; j < FB_RPB; ++j)
            xt[t][j] = X[(size_t)rows_sh[j] * D_DIM + t];
        __syncthreads();

        const int k0 = sl * 512 + t * 2;
        double s0[FB_RPB], s1[FB_RPB], q0 = 0.0, q1 = 0.0;
        #pragma unroll
        for (int j = 0; j < FB_RPB; ++j) { s0[j] = 0.0; s1[j] = 0.0; }
        for (int d = 0; d < D_DIM; ++d) {
            f2 ev = *(const f2*)(E + (size_t)d * K_CODES + k0);
            double e0d = (double)ev[0], e1d = (double)ev[1];
            const f4* xp = (const f4*)(&xt[d][0]);
            f4 xa = xp[0], xb = xp[1];
            double xd[FB_RPB] = { (double)xa[0], (double)xa[1], (double)xa[2], (double)xa[3],
                                  (double)xb[0], (double)xb[1], (double)xb[2], (double)xb[3] };
            q0 += e0d * e0d; q1 += e1d * e1d;
            #pragma unroll
            for (int j = 0; j < FB_RPB; ++j) {
                s0[j] += xd[j] * e0d;
                s1[j] += xd[j] * e1d;
            }
        }
        double bv[FB_RPB]; int bi[FB_RPB];
        #pragma unroll
        for (int j = 0; j < FB_RPB; ++j) {
            double k0v = q0 - 2.0 * s0[j];
            double k1v = q1 - 2.0 * s1[j];
            bv[j] = k0v; bi[j] = k0;
            if (k1v < bv[j]) { bv[j] = k1v; bi[j] = k0 + 1; }
        }
        #pragma unroll
        for (int off = 1; off < 64; off <<= 1) {
            #pragma unroll
            for (int j = 0; j < FB_RPB; ++j) {
                double ov = __shfl_xor(bv[j], off);
                int    oi = __shfl_xor(bi[j], off);
                if (ov < bv[j] || (ov == bv[j] && oi < bi[j])) { bv[j] = ov; bi[j] = oi; }
            }
        }
        const int wave = t >> 6;
        if ((t & 63) == 0) {
            #pragma unroll
            for (int j = 0; j < FB_RPB; ++j) { wbv[wave][j] = bv[j]; wbi[wave][j] = bi[j]; }
        }
        __syncthreads();
        if (t < FB_RPB) {
            double b = wbv[0][t]; int i_ = wbi[0][t];
            #pragma unroll
            for (int wv = 1; wv < 4; ++wv) {
                double ov = wbv[wv][t]; int oi = wbi[wv][t];
                if (ov < b || (ov == b && oi < i_)) { b = ov; i_ = oi; }
            }
            int e = rc * FB_RPB + t;
            res_v[(size_t)e * RF_SLICES + sl] = b;
            res_i[(size_t)e * RF_SLICES + sl] = i_;
        }
    }
}

// -------- refine phase 2: pick fp64 winner, patch row + loss; last block emits fin --------
__global__ void patch_kernel(const float* __restrict__ X, const float* __restrict__ Et32,
                             float* __restrict__ out, double* __restrict__ loss_sum,
                             const int* __restrict__ counter, const int2* __restrict__ list,
                             const double* __restrict__ res_v, const int* __restrict__ res_i,
                             int* __restrict__ patch_done) {
    int nf = *counter; if (nf > FB_CAP) nf = FB_CAP;
    __shared__ int nc_sh;
    const int t = threadIdx.x;
    for (int b = blockIdx.x; b < nf; b += gridDim.x) {
        __syncthreads();
        if (t == 0) {
            double bv = res_v[(size_t)b * RF_SLICES]; int bi = res_i[(size_t)b * RF_SLICES];
            for (int s = 1; s < RF_SLICES; ++s) {
                double v = res_v[(size_t)b * RF_SLICES + s];
                int    i = res_i[(size_t)b * RF_SLICES + s];
                if (v < bv || (v == bv && i < bi)) { bv = v; bi = i; }
            }
            nc_sh = bi;
        }
        __syncthreads();
        int2 ent = list[b];
        const int oc = ent.y, row = ent.x, nc = nc_sh;
        if (nc != oc) {       // uniform branch across block
            float x  = X[(size_t)row * D_DIM + t];
            float qn = Et32[(size_t)nc * D_DIM + t];
            float qo = Et32[(size_t)oc * D_DIM + t];
            float dqn = qn - x, dqo = qo - x;
            out[(size_t)row * D_DIM + t] = x + dqn;
            double dl = (double)dqn * dqn - (double)dqo * dqo;
            #pragma unroll
            for (int off = 32; off > 0; off >>= 1)
                dl += __shfl_down(dl, off);
            if ((t & 63) == 0) atomicAdd(loss_sum, dl);
        }
    }
    // ---- fin: last block to finish reads total loss and writes the scalar ----
    __threadfence();                 // release our loss adds before the counter bump
    __syncthreads();
    if (t == 0) {
        int old = atomicAdd(patch_done, 1);
        if (old == (int)gridDim.x - 1) {
            double m = atomicAdd(loss_sum, 0.0) / (double)NUM_ELEM;   // RMW read
            out[NUM_ELEM] = (float)(0.25 * m + m);
        }
    }
}

extern "C" void kernel_launch(void* const* d_in, const int* in_sizes, int n_in,
                              void* d_out, int out_size, void* d_ws, size_t ws_size,
                              hipStream_t stream) {
    const float* X = (const float*)d_in[0];   // [32,1024,256] fp32
    const float* E = (const float*)d_in[1];   // [256,8192] fp32
    float* out = (float*)d_out;

    // ws layout (ctl region [0,8192) zeroed by prep block 0)
    double* loss_sum   = (double*)d_ws;                        // @0 (8 B)
    int*    counter    = (int*)((char*)d_ws + 8);              // @8
    int*    patch_done = (int*)((char*)d_ws + 16);             // @16
    float*  ee         = (float*)((char*)d_ws + 8192);         // 32 KB
    int2*   list       = (int2*)((char*)d_ws + 40960);         // 64 KB
    double* res_v      = (double*)((char*)d_ws + 131072);      // 1 MB (8192 x 16 x 8B)
    int*    res_i      = (int*)((char*)d_ws + 1179648);        // 512 KB
    float*  Et32       = (float*)((char*)d_ws + 1703936);      // 8 MB
    short*  Ep         = (short*)((char*)d_ws + 10092544);     // 4 MB
    f2*     res_bs     = (f2*)((char*)d_ws + 14286848);        // 512 KB
    int*    res_idx    = (int*)((char*)d_ws + 15335424);       // 256 KB

    prep_kernel<<<N_PANELS, 256, 0, stream>>>(E, Ep, Et32, ee, (float*)d_ws);
    mfma_sieve_kernel<<<512, 256, 0, stream>>>(X, Ep, ee, res_bs, res_idx);
    gather_kernel<<<N_ROWS / 128, 256, 0, stream>>>(X, Et32, res_bs, res_idx,
                                                    counter, list, out, loss_sum);
    refine1_kernel<<<2048, 256, 0, stream>>>(X, E, counter, list, res_v, res_i);
    patch_kernel<<<1024, 256, 0, stream>>>(X, Et32, out, loss_sum, counter, list,
                                           res_v, res_i, patch_done);
}

// Round 13
// 326.611 us; speedup vs baseline: 1.5423x; 1.1740x over previous
//
#include <hip/hip_runtime.h>

typedef float f4   __attribute__((ext_vector_type(4)));
typedef float f2   __attribute__((ext_vector_type(2)));
typedef _Float16 f16x8 __attribute__((ext_vector_type(8)));
typedef float f32x4  __attribute__((ext_vector_type(4)));

#define N_ROWS  32768
#define D_DIM   256
#define K_CODES 8192
#define NUM_ELEM (N_ROWS * D_DIM)
#define EPS_MARGIN 2e-3f     // fp16 single-pass sieve: key-diff err sigma ~2.6e-4 -> 7.7 sigma
#define FB_CAP  8192
#define FB_RPB  8
#define RF_SLICES 16
#define N_PANELS 256         // 32 codes per panel
#define HALF_PANELS 128      // panels per code-half
#define HALF_PAIRS 64        // panel-pairs per half (2 panels per barrier)

__device__ __forceinline__ void gl2lds16(const void* g, void* l) {
    __builtin_amdgcn_global_load_lds(
        (const __attribute__((address_space(1))) unsigned int*)g,
        (__attribute__((address_space(3))) unsigned int*)l, 16, 0, 0);
}

// -------- fused prep: ctl-zero + Ep (panel-major fp16) + Et32 (E^T fp32) + ee --------
__global__ void prep_kernel(const float* __restrict__ E, short* __restrict__ Ep,
                            float* __restrict__ Et32, float* __restrict__ ee,
                            float* __restrict__ ctl) {
    __shared__ float eepart[8][32];
    const int p  = blockIdx.x;
    const int t  = threadIdx.x;
    const int c  = t & 31;
    const int gq = t >> 5;
    const int cp = p * 32;
    if (p == 0) {   // zero control region [0, 8192): loss_sum, counter
        f4 z = (f4)(0.0f);
        f4* dst = (f4*)ctl;
        dst[t * 2]     = z;
        dst[t * 2 + 1] = z;
    }
    short* ph = Ep + (size_t)p * 8192;
    float ss = 0.0f;
    #pragma unroll
    for (int gi = 0; gi < 4; ++gi) {
        int g = gq * 4 + gi;
        f16x8 h;
        f4 av, bv;
        #pragma unroll
        for (int j = 0; j < 8; ++j) {
            float v = E[(size_t)(g * 8 + j) * K_CODES + cp + c];
            h[j] = (_Float16)v;   // RNE cvt
            ss += v * v;
            if (j < 4) av[j] = v; else bv[j - 4] = v;
        }
        *(f16x8*)(ph + (g * 32 + c) * 8) = h;
        *(f4*)(Et32 + (size_t)(cp + c) * D_DIM + g * 8)     = av;
        *(f4*)(Et32 + (size_t)(cp + c) * D_DIM + g * 8 + 4) = bv;
    }
    eepart[gq][c] = ss;
    __syncthreads();
    if (t < 32) {
        float s = 0.0f;
        #pragma unroll
        for (int q = 0; q < 8; ++q) s += eepart[q][t];
        ee[cp + t] = s;
    }
}

// -------- MFMA sieve (R12-verified): R7 datapath, 2 panels per barrier --------
// grid 512 = (256 row-tiles x 128 rows) x (2 halves); 64 KB LDS -> 2 blocks/CU
__launch_bounds__(256, 2)
__global__ void mfma_sieve_kernel(const float* __restrict__ X,
                                  const short* __restrict__ Ep,
                                  const float* __restrict__ ee,
                                  f2* __restrict__ res_bs,     // [row*2+half] = (best, sec)
                                  int* __restrict__ res_idx) { // [row*2+half]
    __shared__ __align__(16) short Bbuf[2][16384];  // 2 pair-buffers x 32 KB
    const int t    = threadIdx.x;
    const int w    = t >> 6;
    const int lane = t & 63;
    const int n    = lane & 15;
    const int quad = lane >> 4;
    const int half = blockIdx.x & 1;
    const int row0 = (blockIdx.x >> 1) * 128;
    const int rw   = row0 + w * 32;
    const int p0   = half * HALF_PANELS;

    // ---- A fragments (32 rows x 256 d) -> fp16 registers ----
    f16x8 Ah[2][8];
    #pragma unroll
    for (int rt = 0; rt < 2; ++rt) {
        const float* xp = X + (size_t)(rw + rt * 16 + n) * D_DIM;
        #pragma unroll
        for (int ks = 0; ks < 8; ++ks) {
            int d = ks * 32 + quad * 8;
            f4 a = *(const f4*)(xp + d);
            f4 b = *(const f4*)(xp + d + 4);
            f16x8 h;
            #pragma unroll
            for (int j = 0; j < 8; ++j) {
                float x = (j < 4) ? a[j] : b[j - 4];
                h[j] = (_Float16)x;
            }
            Ah[rt][ks] = h;
        }
    }

    float bestv[8], secv[8]; int besti[8];
    #pragma unroll
    for (int s = 0; s < 8; ++s) { bestv[s] = 1e30f; secv[s] = 1e30f; besti[s] = 0; }

    {   // prime pair 0 (panels p0, p0+1) -> Bbuf[0] (32 KB: 8 gl2lds per wave)
        const char* gp = (const char*)Ep + (size_t)p0 * 16384;
        char* lp = (char*)&Bbuf[0][0];
        #pragma unroll
        for (int i = 0; i < 8; ++i)
            gl2lds16(gp + (w * 8 + i) * 1024 + lane * 16, lp + (w * 8 + i) * 1024);
    }
    __syncthreads();

    for (int ii = 0; ii < HALF_PAIRS; ++ii) {
        const int pbuf = ii & 1;
        if (ii + 1 < HALF_PAIRS) {   // prefetch next pair (32 KB)
            const char* gp = (const char*)Ep + (size_t)(p0 + 2 * (ii + 1)) * 16384;
            char* lp = (char*)&Bbuf[pbuf ^ 1][0];
            #pragma unroll
            for (int k = 0; k < 8; ++k)
                gl2lds16(gp + (w * 8 + k) * 1024 + lane * 16, lp + (w * 8 + k) * 1024);
        }

        #pragma unroll
        for (int sub = 0; sub < 2; ++sub) {
            const int p = p0 + 2 * ii + sub;
            const short* Bh = &Bbuf[pbuf][sub * 8192];

            f32x4 acc[2][2];
            #pragma unroll
            for (int ct = 0; ct < 2; ++ct)
                #pragma unroll
                for (int rt = 0; rt < 2; ++rt)
                    acc[ct][rt] = (f32x4)(0.0f);

            #pragma unroll
            for (int ks = 0; ks < 8; ++ks) {
                const int g = ks * 4 + quad;
                f16x8 bh[2];
                #pragma unroll
                for (int ct = 0; ct < 2; ++ct) {
                    int c = ct * 16 + n;
                    bh[ct] = *(const f16x8*)(Bh + (g * 32 + c) * 8);
                }
                #pragma unroll
                for (int ct = 0; ct < 2; ++ct)
                    #pragma unroll
                    for (int rt = 0; rt < 2; ++rt)
                        acc[ct][rt] = __builtin_amdgcn_mfma_f32_16x16x32_f16(Ah[rt][ks], bh[ct], acc[ct][rt], 0, 0, 0);
            }

            const int cb = p * 32;
            #pragma unroll
            for (int ct = 0; ct < 2; ++ct) {
                int code = cb + ct * 16 + n;
                float eev = ee[code];
                #pragma unroll
                for (int rt = 0; rt < 2; ++rt)
                    #pragma unroll
                    for (int r = 0; r < 4; ++r) {
                        float key = fmaf(-2.0f, acc[ct][rt][r], eev);
                        int s = rt * 4 + r;
                        // min/max form; strict-< index semantics preserved
                        float nb = fminf(key, bestv[s]);
                        secv[s]  = fminf(secv[s], fmaxf(key, bestv[s]));
                        besti[s] = (key < bestv[s]) ? code : besti[s];
                        bestv[s] = nb;
                    }
            }
        }
        __syncthreads();   // one barrier per 2 panels
    }

    // top-2 merge across the 16 'n' lanes
    #pragma unroll
    for (int off = 1; off < 16; off <<= 1) {
        #pragma unroll
        for (int s = 0; s < 8; ++s) {
            float ov = __shfl_xor(bestv[s], off);
            int   oi = __shfl_xor(besti[s], off);
            float os = __shfl_xor(secv[s], off);
            bool owin = (ov < bestv[s]) || (ov == bestv[s] && oi < besti[s]);
            if (owin) { secv[s] = fminf(os, bestv[s]); bestv[s] = ov; besti[s] = oi; }
            else      { secv[s] = fminf(secv[s], ov); }
        }
    }

    if (n == 0) {
        #pragma unroll
        for (int s = 0; s < 8; ++s) {
            int rl  = w * 32 + (s >> 2) * 16 + quad * 4 + (s & 3);
            int row = row0 + rl;
            f2 bs; bs[0] = bestv[s]; bs[1] = secv[s];
            res_bs[(size_t)row * 2 + half]  = bs;
            res_idx[(size_t)row * 2 + half] = besti[s];
        }
    }
}

// -------- fused merge(2 halves)+flag + gather + straight-through output + loss (R7) --------
__global__ void gather_kernel(const float* __restrict__ X, const float* __restrict__ Et32,
                              const f2* __restrict__ res_bs, const int* __restrict__ res_idx,
                              int* __restrict__ counter, int2* __restrict__ list,
                              float* __restrict__ out, double* __restrict__ loss_sum) {
    __shared__ int bl_[128];
    const int t    = threadIdx.x;
    const int row0 = blockIdx.x * 128;
    if (t < 128) {
        const int row = row0 + t;
        f2 a = res_bs[(size_t)row * 2];      // half 0 (indices < half 1's)
        f2 b = res_bs[(size_t)row * 2 + 1];
        int ia = res_idx[(size_t)row * 2];
        int ib = res_idx[(size_t)row * 2 + 1];
        float gb; int gi; float gs;
        if (b[0] < a[0]) { gb = b[0]; gi = ib; gs = fminf(b[1], a[0]); }
        else             { gb = a[0]; gi = ia; gs = fminf(a[1], b[0]); }  // tie -> half 0 (lower idx)
        bl_[t] = gi;
        if (gs - gb <= EPS_MARGIN) {
            int pos = atomicAdd(counter, 1);
            if (pos < FB_CAP) list[pos] = make_int2(row, gi);
        }
    }
    __syncthreads();
    double ls = 0.0;
    const int d = t;
    #pragma unroll 4
    for (int r = 0; r < 128; ++r) {
        int code = bl_[r];
        float q  = Et32[(size_t)code * D_DIM + d];
        float x  = X[(size_t)(row0 + r) * D_DIM + d];
        float dq = q - x;
        out[(size_t)(row0 + r) * D_DIM + d] = x + dq;
        ls += (double)dq * (double)dq;
    }
    #pragma unroll
    for (int off = 32; off > 0; off >>= 1)
        ls += __shfl_down(ls, off);
    if ((t & 63) == 0) atomicAdd(loss_sum, ls);
}

// -------- refine phase 1 (R7): fp64 keys over (row-chunk x 16 slices) --------
__global__ void refine1_kernel(const float* __restrict__ X, const float* __restrict__ E,
                               const int* __restrict__ counter, const int2* __restrict__ list,
                               double* __restrict__ res_v, int* __restrict__ res_i) {
    __shared__ float xt[D_DIM][FB_RPB];
    __shared__ int rows_sh[FB_RPB];
    __shared__ double wbv[4][FB_RPB];
    __shared__ int    wbi[4][FB_RPB];

    int nf = *counter; if (nf > FB_CAP) nf = FB_CAP;
    const int nchunks = (nf + FB_RPB - 1) / FB_RPB;
    const int nitems  = nchunks * RF_SLICES;
    const int t = threadIdx.x;

    for (int item = blockIdx.x; item < nitems; item += gridDim.x) {
        const int rc = item / RF_SLICES;
        const int sl = item % RF_SLICES;
        __syncthreads();
        if (t < FB_RPB) {
            int e = rc * FB_RPB + t;
            int2 ent = list[(e < nf) ? e : 0];
            rows_sh[t] = ent.x;
        }
        __syncthreads();
        #pragma unroll
        for (int j = 0; j < FB_RPB; ++j)
            xt[t][j] = X[(size_t)rows_sh[j] * D_DIM + t];
        __syncthreads();

        const int k0 = sl * 512 + t * 2;
        double s0[FB_RPB], s1[FB_RPB], q0 = 0.0, q1 = 0.0;
        #pragma unroll
        for (int j = 0; j < FB_RPB; ++j) { s0[j] = 0.0; s1[j] = 0.0; }
        for (int d = 0; d < D_DIM; ++d) {
            f2 ev = *(const f2*)(E + (size_t)d * K_CODES + k0);
            double e0d = (double)ev[0], e1d = (double)ev[1];
            const f4* xp = (const f4*)(&xt[d][0]);
            f4 xa = xp[0], xb = xp[1];
            double xd[FB_RPB] = { (double)xa[0], (double)xa[1], (double)xa[2], (double)xa[3],
                                  (double)xb[0], (double)xb[1], (double)xb[2], (double)xb[3] };
            q0 += e0d * e0d; q1 += e1d * e1d;
            #pragma unroll
            for (int j = 0; j < FB_RPB; ++j) {
                s0[j] += xd[j] * e0d;
                s1[j] += xd[j] * e1d;
            }
        }
        double bv[FB_RPB]; int bi[FB_RPB];
        #pragma unroll
        for (int j = 0; j < FB_RPB; ++j) {
            double k0v = q0 - 2.0 * s0[j];
            double k1v = q1 - 2.0 * s1[j];
            bv[j] = k0v; bi[j] = k0;
            if (k1v < bv[j]) { bv[j] = k1v; bi[j] = k0 + 1; }
        }
        #pragma unroll
        for (int off = 1; off < 64; off <<= 1) {
            #pragma unroll
            for (int j = 0; j < FB_RPB; ++j) {
                double ov = __shfl_xor(bv[j], off);
                int    oi = __shfl_xor(bi[j], off);
                if (ov < bv[j] || (ov == bv[j] && oi < bi[j])) { bv[j] = ov; bi[j] = oi; }
            }
        }
        const int wave = t >> 6;
        if ((t & 63) == 0) {
            #pragma unroll
            for (int j = 0; j < FB_RPB; ++j) { wbv[wave][j] = bv[j]; wbi[wave][j] = bi[j]; }
        }
        __syncthreads();
        if (t < FB_RPB) {
            double b = wbv[0][t]; int i_ = wbi[0][t];
            #pragma unroll
            for (int wv = 1; wv < 4; ++wv) {
                double ov = wbv[wv][t]; int oi = wbi[wv][t];
                if (ov < b || (ov == b && oi < i_)) { b = ov; i_ = oi; }
            }
            int e = rc * FB_RPB + t;
            res_v[(size_t)e * RF_SLICES + sl] = b;
            res_i[(size_t)e * RF_SLICES + sl] = i_;
        }
    }
}

// -------- refine phase 2 (R7): pick fp64 winner, patch row + loss --------
__global__ void patch_kernel(const float* __restrict__ X, const float* __restrict__ Et32,
                             float* __restrict__ out, double* __restrict__ loss_sum,
                             const int* __restrict__ counter, const int2* __restrict__ list,
                             const double* __restrict__ res_v, const int* __restrict__ res_i) {
    int nf = *counter; if (nf > FB_CAP) nf = FB_CAP;
    const int b = blockIdx.x;
    if (b >= nf) return;
    __shared__ int nc_sh;
    const int t = threadIdx.x;
    if (t == 0) {
        double bv = res_v[(size_t)b * RF_SLICES]; int bi = res_i[(size_t)b * RF_SLICES];
        for (int s = 1; s < RF_SLICES; ++s) {
            double v = res_v[(size_t)b * RF_SLICES + s];
            int    i = res_i[(size_t)b * RF_SLICES + s];
            if (v < bv || (v == bv && i < bi)) { bv = v; bi = i; }
        }
        nc_sh = bi;
    }
    __syncthreads();
    int2 ent = list[b];
    const int oc = ent.y, row = ent.x, nc = nc_sh;
    if (nc == oc) return;
    float x  = X[(size_t)row * D_DIM + t];
    float qn = Et32[(size_t)nc * D_DIM + t];
    float qo = Et32[(size_t)oc * D_DIM + t];
    float dqn = qn - x, dqo = qo - x;
    out[(size_t)row * D_DIM + t] = x + dqn;
    double dl = (double)dqn * dqn - (double)dqo * dqo;
    #pragma unroll
    for (int off = 32; off > 0; off >>= 1)
        dl += __shfl_down(dl, off);
    if ((t & 63) == 0) atomicAdd(loss_sum, dl);
}

// -------- finalize loss --------
__global__ void fin_kernel(const double* __restrict__ loss_sum, float* __restrict__ out) {
    double m = loss_sum[0] / (double)NUM_ELEM;
    out[NUM_ELEM] = (float)(0.25 * m + m);
}

extern "C" void kernel_launch(void* const* d_in, const int* in_sizes, int n_in,
                              void* d_out, int out_size, void* d_ws, size_t ws_size,
                              hipStream_t stream) {
    const float* X = (const float*)d_in[0];   // [32,1024,256] fp32
    const float* E = (const float*)d_in[1];   // [256,8192] fp32
    float* out = (float*)d_out;

    // ws layout (ctl region [0,8192) zeroed by prep block 0)
    double* loss_sum = (double*)d_ws;                          // @0 (8 B)
    int*    counter  = (int*)((char*)d_ws + 8);                // @8
    float*  ee       = (float*)((char*)d_ws + 8192);           // 32 KB
    int2*   list     = (int2*)((char*)d_ws + 40960);           // 64 KB
    double* res_v    = (double*)((char*)d_ws + 131072);        // 1 MB (8192 x 16 x 8B)
    int*    res_i    = (int*)((char*)d_ws + 1179648);          // 512 KB
    float*  Et32     = (float*)((char*)d_ws + 1703936);        // 8 MB
    short*  Ep       = (short*)((char*)d_ws + 10092544);       // 4 MB
    f2*     res_bs   = (f2*)((char*)d_ws + 14286848);          // 512 KB
    int*    res_idx  = (int*)((char*)d_ws + 15335424);         // 256 KB

    prep_kernel<<<N_PANELS, 256, 0, stream>>>(E, Ep, Et32, ee, (float*)d_ws);
    mfma_sieve_kernel<<<512, 256, 0, stream>>>(X, Ep, ee, res_bs, res_idx);
    gather_kernel<<<N_ROWS / 128, 256, 0, stream>>>(X, Et32, res_bs, res_idx,
                                                    counter, list, out, loss_sum);
    refine1_kernel<<<2048, 256, 0, stream>>>(X, E, counter, list, res_v, res_i);
    patch_kernel<<<FB_CAP, 256, 0, stream>>>(X, Et32, out, loss_sum, counter, list,
                                             res_v, res_i);
    fin_kernel<<<1, 1, 0, stream>>>(loss_sum, out);
}